// Round 4
// baseline (363.805 us; speedup 1.0000x reference)
//
#include <hip/hip_runtime.h>

// KoopmanOperator: y_{t+1} = K(MLPs(y_t)) * y_t, 64 steps, B=4096 rows, K=192.
// Inputs f32 (proven by R1 NaN signature); output assumed FLOAT32 (reference
// output dtype, per harness contract). One WG per 16 batch rows; weights in
// per-wave bf16 MFMA B-fragments (registers); y state f32 in LDS + bf16 shadow
// for MFMA A-operands. 256 WGs x 256 threads = 1 WG/CU.

typedef unsigned short u16;
typedef __attribute__((ext_vector_type(8))) short bf16x8;
typedef __attribute__((ext_vector_type(4))) float f32x4;

#define KD   192
#define TT   64
#define DTC  0.01f

#define Y16S 200
#define Y32S 196
#define H1S  136
#define R1S  72
#define H32S 132
#define RES  68

static __device__ __forceinline__ u16 f2b(float f) {  // f32 -> bf16 RNE
    union { float f; unsigned int u; } v;
    v.f = f;
    unsigned int u = v.u;
    return (u16)((u + 0x7FFFu + ((u >> 16) & 1u)) >> 16);
}

static __device__ __forceinline__ bf16x8 pack8(const float* __restrict__ p) {
    bf16x8 r;
#pragma unroll
    for (int j = 0; j < 8; ++j) r[j] = (short)f2b(p[j]);
    return r;
}

__global__ __launch_bounds__(256, 1)
void koopman_kernel(const float* __restrict__ x,
                    const float* __restrict__ cW1, const float* __restrict__ cb1,
                    const float* __restrict__ cW2, const float* __restrict__ cb2,
                    const float* __restrict__ rW1, const float* __restrict__ rb1,
                    const float* __restrict__ rW2, const float* __restrict__ rb2,
                    float* __restrict__ out)
{
    __shared__ __align__(16) u16   y16[16 * Y16S];
    __shared__ __align__(16) float y32[16 * Y32S];
    __shared__ __align__(16) u16   h1r[16 * H1S];
    __shared__ __align__(16) u16   r1r[16 * R1S];
    __shared__ __align__(16) float h32[16 * H32S];
    __shared__ __align__(16) float re32[16 * RES];

    const int tid  = threadIdx.x;
    const int wave = tid >> 6;
    const int lane = tid & 63;
    const int l16  = lane & 15;
    const int quad = lane >> 4;
    const int row0 = blockIdx.x << 4;

    const int n0  = wave << 5;
    const int n0r = wave << 4;

    // ---- runtime layout probes (verified identical to docs in R3; kept as guard) ----
    int m_eff[4], n_eff[4];
    {
        bf16x8 pl, pone;
        short lv = (short)f2b((float)l16);
        short on = (short)0x3F80;
#pragma unroll
        for (int j = 0; j < 8; ++j) { pl[j] = lv; pone[j] = on; }
        f32x4 zz = {0.f, 0.f, 0.f, 0.f};
        f32x4 dm = __builtin_amdgcn_mfma_f32_16x16x32_bf16(pl, pone, zz, 0, 0, 0);
        f32x4 dn = __builtin_amdgcn_mfma_f32_16x16x32_bf16(pone, pl, zz, 0, 0, 0);
#pragma unroll
        for (int r = 0; r < 4; ++r) {
            m_eff[r] = (((int)dm[r]) >> 5) & 15;
            n_eff[r] = (((int)dn[r]) >> 5) & 15;
        }
    }

    // ---- step-invariant weight B-fragments (f32 -> bf16 RNE) ----
    bf16x8 wc1[6][2];
    bf16x8 wc2[4][2];
    bf16x8 wr1[6];
    bf16x8 wr2[2];
#pragma unroll
    for (int kt = 0; kt < 6; ++kt) {
#pragma unroll
        for (int nt = 0; nt < 2; ++nt)
            wc1[kt][nt] = pack8(cW1 + (n0 + nt * 16 + l16) * KD + kt * 32 + quad * 8);
        wr1[kt] = pack8(rW1 + (n0r + l16) * KD + kt * 32 + quad * 8);
    }
#pragma unroll
    for (int kt = 0; kt < 4; ++kt)
#pragma unroll
        for (int nt = 0; nt < 2; ++nt)
            wc2[kt][nt] = pack8(cW2 + (n0 + nt * 16 + l16) * 128 + kt * 32 + quad * 8);
#pragma unroll
    for (int kt = 0; kt < 2; ++kt)
        wr2[kt] = pack8(rW2 + (n0r + l16) * 64 + kt * 32 + quad * 8);

    float cb1A[4], cb1B[4], cb2A[4], cb2B[4], rb1A[4], rb2A[4];
#pragma unroll
    for (int r = 0; r < 4; ++r) {
        int nc = n0 + n_eff[r];
        cb1A[r] = cb1[nc];      cb1B[r] = cb1[nc + 16];
        cb2A[r] = cb2[nc];      cb2B[r] = cb2[nc + 16];
        int nr_ = n0r + n_eff[r];
        rb1A[r] = rb1[nr_];     rb2A[r] = rb2[nr_];
    }

    // ---- init y from x[:, 0, :] ----
    for (int idx = tid; idx < 16 * KD; idx += 256) {
        int r = idx / KD, c = idx - r * KD;
        float v = x[(size_t)(row0 + r) * (TT * KD) + c];
        y16[r * Y16S + c] = f2b(v);
        y32[r * Y32S + c] = v;
    }
    __syncthreads();

    for (int t = 0; t < TT; ++t) {
        // ---- Phase A: h1 = relu(y@cW1^T + cb1); r1 = relu(y@rW1^T + rb1) ----
        bf16x8 ya[6];
#pragma unroll
        for (int kt = 0; kt < 6; ++kt)
            ya[kt] = *reinterpret_cast<const bf16x8*>(
                &y16[l16 * Y16S + kt * 32 + quad * 8]);
        f32x4 ah0 = {0.f, 0.f, 0.f, 0.f};
        f32x4 ah1 = {0.f, 0.f, 0.f, 0.f};
        f32x4 ar  = {0.f, 0.f, 0.f, 0.f};
#pragma unroll
        for (int kt = 0; kt < 6; ++kt) {
            ah0 = __builtin_amdgcn_mfma_f32_16x16x32_bf16(ya[kt], wc1[kt][0], ah0, 0, 0, 0);
            ah1 = __builtin_amdgcn_mfma_f32_16x16x32_bf16(ya[kt], wc1[kt][1], ah1, 0, 0, 0);
            ar  = __builtin_amdgcn_mfma_f32_16x16x32_bf16(ya[kt], wr1[kt],  ar,  0, 0, 0);
        }
#pragma unroll
        for (int r = 0; r < 4; ++r) {
            int orow = m_eff[r];
            int ocA  = n0 + n_eff[r];
            int ocR  = n0r + n_eff[r];
            h1r[orow * H1S + ocA]      = f2b(fmaxf(ah0[r] + cb1A[r], 0.f));
            h1r[orow * H1S + ocA + 16] = f2b(fmaxf(ah1[r] + cb1B[r], 0.f));
            r1r[orow * R1S + ocR]      = f2b(fmaxf(ar[r]  + rb1A[r], 0.f));
        }
        __syncthreads();

        // ---- Phase B: h = h1@cW2^T + cb2; re = r1@rW2^T + rb2 ----
        bf16x8 ha[4], ra[2];
#pragma unroll
        for (int kt = 0; kt < 4; ++kt)
            ha[kt] = *reinterpret_cast<const bf16x8*>(
                &h1r[l16 * H1S + kt * 32 + quad * 8]);
#pragma unroll
        for (int kt = 0; kt < 2; ++kt)
            ra[kt] = *reinterpret_cast<const bf16x8*>(
                &r1r[l16 * R1S + kt * 32 + quad * 8]);
        f32x4 bh0 = {0.f, 0.f, 0.f, 0.f};
        f32x4 bh1 = {0.f, 0.f, 0.f, 0.f};
        f32x4 bre = {0.f, 0.f, 0.f, 0.f};
#pragma unroll
        for (int kt = 0; kt < 4; ++kt) {
            bh0 = __builtin_amdgcn_mfma_f32_16x16x32_bf16(ha[kt], wc2[kt][0], bh0, 0, 0, 0);
            bh1 = __builtin_amdgcn_mfma_f32_16x16x32_bf16(ha[kt], wc2[kt][1], bh1, 0, 0, 0);
        }
#pragma unroll
        for (int kt = 0; kt < 2; ++kt)
            bre = __builtin_amdgcn_mfma_f32_16x16x32_bf16(ra[kt], wr2[kt], bre, 0, 0, 0);
#pragma unroll
        for (int r = 0; r < 4; ++r) {
            int orow = m_eff[r];
            int ocA  = n0 + n_eff[r];
            int ocR  = n0r + n_eff[r];
            h32[orow * H32S + ocA]      = bh0[r] + cb2A[r];
            h32[orow * H32S + ocA + 16] = bh1[r] + cb2B[r];
            re32[orow * RES + ocR]      = bre[r] + rb2A[r];
        }
        __syncthreads();

        // ---- Phase C: elementwise rotation/scale update, f32 store of y_t ----
        {
            const int cr = tid >> 4;
            const int ci = (tid & 15) << 2;
            float* og = out + ((size_t)(row0 + cr) * TT + t) * KD;

            float buf[8];
            unsigned int pk[4];
#pragma unroll
            for (int u = 0; u < 4; ++u) {
                int i = ci + u;
                float mu = h32[cr * H32S + 2 * i];
                float om = h32[cr * H32S + 2 * i + 1];
                float e = __expf(DTC * mu);
                float sn, cs;
                __sincosf(DTC * om, &sn, &cs);
                float ye = y32[cr * Y32S + 2 * i];
                float yo = y32[cr * Y32S + 2 * i + 1];
                float ne = e * (cs * ye - sn * yo);
                float no = e * (sn * ye + cs * yo);
                y32[cr * Y32S + 2 * i]     = ne;
                y32[cr * Y32S + 2 * i + 1] = no;
                buf[2 * u]     = ne;
                buf[2 * u + 1] = no;
                pk[u] = (unsigned int)f2b(ne) | ((unsigned int)f2b(no) << 16);
            }
            uint4 v4;
            v4.x = pk[0]; v4.y = pk[1]; v4.z = pk[2]; v4.w = pk[3];
            *reinterpret_cast<uint4*>(&y16[cr * Y16S + 2 * ci]) = v4;
            float4 f0, f1;
            f0.x = buf[0]; f0.y = buf[1]; f0.z = buf[2]; f0.w = buf[3];
            f1.x = buf[4]; f1.y = buf[5]; f1.z = buf[6]; f1.w = buf[7];
            *reinterpret_cast<float4*>(og + 2 * ci)     = f0;
            *reinterpret_cast<float4*>(og + 2 * ci + 4) = f1;

            float rbuf[4];
            unsigned int pk2[2];
#pragma unroll
            for (int u = 0; u < 4; ++u) {
                int i = ci + u;
                float rv = re32[cr * RES + i];
                float yr = y32[cr * Y32S + 128 + i] * __expf(DTC * rv);
                y32[cr * Y32S + 128 + i] = yr;
                rbuf[u] = yr;
                unsigned int b = f2b(yr);
                if (u & 1) pk2[u >> 1] |= (b << 16); else pk2[u >> 1] = b;
            }
            uint2 v2;
            v2.x = pk2[0]; v2.y = pk2[1];
            *reinterpret_cast<uint2*>(&y16[cr * Y16S + 128 + ci]) = v2;
            float4 fr;
            fr.x = rbuf[0]; fr.y = rbuf[1]; fr.z = rbuf[2]; fr.w = rbuf[3];
            *reinterpret_cast<float4*>(og + 128 + ci) = fr;
        }
        __syncthreads();
    }
}

extern "C" void kernel_launch(void* const* d_in, const int* in_sizes, int n_in,
                              void* d_out, int out_size, void* d_ws, size_t ws_size,
                              hipStream_t stream) {
    (void)out_size; (void)d_ws; (void)ws_size;
    // Defensive input resolution by element count (identity if doc order holds).
    // Expected: x=50331648, cW1=24576, cb1=128, cW2=16384, cb2=128,
    //           rW1=12288, rb1=64, rW2=4096, rb2=64, (T=1)
    int ix = 0, icW1 = 1, icb1 = 2, icW2 = 3, icb2 = 4;
    int irW1 = 5, irb1 = 6, irW2 = 7, irb2 = 8;
    {
        int first128 = -1, second128 = -1, first64 = -1, second64 = -1;
        int fx = -1, fcW1 = -1, fcW2 = -1, frW1 = -1, frW2 = -1;
        for (int i = 0; i < n_in; ++i) {
            int s = in_sizes[i];
            if (s == 50331648) fx = i;
            else if (s == 24576) fcW1 = i;
            else if (s == 16384) fcW2 = i;
            else if (s == 12288) frW1 = i;
            else if (s == 4096)  frW2 = i;
            else if (s == 128) { if (first128 < 0) first128 = i; else second128 = i; }
            else if (s == 64)  { if (first64  < 0) first64  = i; else second64  = i; }
        }
        if (fx >= 0 && fcW1 >= 0 && fcW2 >= 0 && frW1 >= 0 && frW2 >= 0 &&
            second128 >= 0 && second64 >= 0) {
            ix = fx; icW1 = fcW1; icW2 = fcW2; irW1 = frW1; irW2 = frW2;
            icb1 = first128; icb2 = second128; irb1 = first64; irb2 = second64;
        }
    }
    const float* x   = (const float*)d_in[ix];
    const float* cW1 = (const float*)d_in[icW1];
    const float* cb1 = (const float*)d_in[icb1];
    const float* cW2 = (const float*)d_in[icW2];
    const float* cb2 = (const float*)d_in[icb2];
    const float* rW1 = (const float*)d_in[irW1];
    const float* rb1 = (const float*)d_in[irb1];
    const float* rW2 = (const float*)d_in[irW2];
    const float* rb2 = (const float*)d_in[irb2];
    float* out = (float*)d_out;
    koopman_kernel<<<dim3(256), dim3(256), 0, stream>>>(
        x, cW1, cb1, cW2, cb2, rW1, rb1, rW2, rb2, out);
}